// Round 14
// baseline (396.359 us; speedup 1.0000x reference)
//
#include <hip/hip_runtime.h>

#define DEV __device__ __forceinline__

typedef __bf16 bf16x8 __attribute__((ext_vector_type(8)));
typedef float f32x4 __attribute__((ext_vector_type(4)));
typedef short s16x8 __attribute__((ext_vector_type(8)));
typedef unsigned short u16x4 __attribute__((ext_vector_type(4)));
typedef unsigned short u16x8 __attribute__((ext_vector_type(8)));

constexpr int B_ = 8192;   // batch
constexpr int S_ = 3072;   // z dim
constexpr int H_ = 100;    // hidden
constexpr int NP_ = 128;   // padded hidden
constexpr int C_ = 1024;   // control dim
constexpr int KS_ = 64;    // K-step for GEMM1
constexpr int NSPLIT_ = 4; // K-split factor
constexpr int KSP_ = S_ / NSPLIT_;       // 768 per split
constexpr int NIT_ = KSP_ / KS_;         // 12 iters per block

// workspace layout (bytes)
constexpr size_t OFF_W1b = 0;                                   // [128 n][3072 k] bf16
constexpr size_t OFF_W2b = OFF_W1b + (size_t)NP_ * S_ * 2;      // [128 n][128 k] bf16
constexpr size_t OFF_W3c = OFF_W2b + (size_t)NP_ * NP_ * 2;     // [1024 n][128 k] bf16
constexpr size_t OFF_b3c = OFF_W3c + (size_t)C_ * NP_ * 2;      // [1024] f32
constexpr size_t OFF_part = OFF_b3c + (size_t)C_ * 4;           // [4][8192][128] bf16
constexpr size_t OFF_cnt = OFF_part + (size_t)NSPLIT_ * B_ * NP_ * 2;  // [256] u32

DEV unsigned short f2bf(float f) {
  union { float f; unsigned u; } x; x.f = f;
  return (unsigned short)((x.u + 0x7FFFu + ((x.u >> 16) & 1u)) >> 16);
}

DEV float bf2f(unsigned short us) {
  union { unsigned u; float f; } x; x.u = ((unsigned)us) << 16;
  return x.f;
}

DEV float lambertw0(float x) {
  float w = log1pf(x);
#pragma unroll
  for (int i = 0; i < 10; ++i) {
    float ew = expf(w);
    float f = fmaf(w, ew, -x);
    float wp1 = w + 1.0f;
    float den = ew * wp1 - (w + 2.0f) * f / (2.0f * wp1);
    w = w - f / den;
  }
  return w;
}

DEV void gload16(const void* g, void* l) {
  __builtin_amdgcn_global_load_lds((const __attribute__((address_space(1))) unsigned int*)g,
                                   (__attribute__((address_space(3))) unsigned int*)l, 16, 0, 0);
}

// ---------------- prep: pack weights + zero completion counters ----------------
__global__ void k0_prep(const float* __restrict__ W1, const float* __restrict__ W2,
                        const float* __restrict__ W3, const float* __restrict__ b3,
                        unsigned char* __restrict__ ws) {
  int idx = blockIdx.x * 256 + threadIdx.x;
  constexpr int R1 = NP_ * S_;
  constexpr int R2 = R1 + NP_ * NP_;
  constexpr int R3 = R2 + C_ * NP_;
  constexpr int R4 = R3 + C_;
  constexpr int R5 = R4 + 256;
  if (idx < R1) {
    int n = idx / S_, k = idx - n * S_;
    float v = (n < H_) ? W1[(size_t)(k + 1) * H_ + n] : 0.0f;  // row 0 of W1 = t weights
    ((unsigned short*)(ws + OFF_W1b))[idx] = f2bf(v);
  } else if (idx < R2) {
    int j = idx - R1;
    int n = j >> 7, k = j & 127;
    float v = (n < H_ && k < H_) ? W2[(size_t)k * H_ + n] : 0.0f;
    ((unsigned short*)(ws + OFF_W2b))[j] = f2bf(v);
  } else if (idx < R3) {
    int j = idx - R2;
    int n = j >> 7, k = j & 127;
    float v = 0.0f;
    if (k < H_) {
      int a = n >> 2, cmp = n & 3;
      const float* row = W3 + (size_t)k * S_ + a * 12;
      v = (cmp == 0) ? 2.0f * (row[6] + row[7] + row[8]) : row[8 + cmp];  // /MASS = *2
    }
    ((unsigned short*)(ws + OFF_W3c))[j] = f2bf(v);
  } else if (idx < R4) {
    int n = idx - R3;
    int a = n >> 2, cmp = n & 3;
    const float* row = b3 + a * 12;
    float v = (cmp == 0) ? 2.0f * (row[6] + row[7] + row[8]) : row[8 + cmp];
    ((float*)(ws + OFF_b3c))[n] = v;
  } else if (idx < R5) {
    ((unsigned*)(ws + OFF_cnt))[idx - R4] = 0u;
  }
}

// ---------------- K1+K2 fused via last-arriver: GEMM1 partials, then the 4th block of
// each row-tile executes the full MLP tail + LambertW head for those 32 rows inline.
// k1 part = R12's proven 50.3us kernel verbatim (bf16 partials). k2-part re-expressed
// for 256 thr / reused 40KB LDS; MFMA order identical to R12 -> output bit-identical.
__global__ __launch_bounds__(256, 3) void k1k2(
    const float* __restrict__ z, const float* __restrict__ t,
    const float* __restrict__ W1, const float* __restrict__ b1,
    const float* __restrict__ b2, const unsigned char* __restrict__ wsr,
    unsigned short* __restrict__ part, unsigned int* __restrict__ cnt,
    float* __restrict__ uo) {
  __shared__ __align__(16) unsigned char lds[40 * 1024];
  unsigned char* ldsA = lds;          // k1: 2x4KB A dbuf | k2: h-tile(4K) + s_part/k/flag
  unsigned char* ldsB = lds + 8192;   // k1: 2x16KB B dbuf | k2: W2/W3c half-tiles

  const int tid = threadIdx.x;
  const int lane = tid & 63;
  const int w = tid >> 6;
  const int m = w & 1;
  const int q = w >> 1;
  const int bid = blockIdx.x;
  const int rt = bid >> 2;
  const int h = bid & 3;
  const int rowbase = rt * 32;
  const int k0 = h * KSP_;

  const unsigned short* W1b = (const unsigned short*)(wsr + OFF_W1b);

  // ---- k1 part (R12 verbatim) ----
  const int arow0 = tid >> 4;             // 0..15
  const float* zp = z + (size_t)(rowbase + arow0) * S_ + k0 + (tid & 15) * 4;
  const int aswz = ((arow0 & 7) << 4);
  const int abyte0 = arow0 * 128 + (tid & 15) * 8;
  const int abyte1 = (arow0 + 16) * 128 + (tid & 15) * 8;

  const int w4 = w * 4;
  const unsigned short* bsrc = W1b + (size_t)(w4 * 8 + (lane >> 3)) * S_ + k0
                               + (((lane & 7) ^ (lane >> 3)) * 8);

  const int r0k = m * 16 + (lane & 15);
  const int kb0 = (lane >> 4) * 16;

  f32x4 acc[4];
#pragma unroll
  for (int e = 0; e < 4; ++e) acc[e] = f32x4{0.f, 0.f, 0.f, 0.f};

#define GLOAD_B(bufoff, kof) do {                                            \
    _Pragma("unroll")                                                        \
    for (int s = 0; s < 4; ++s)                                              \
      gload16(bsrc + (size_t)s * 8 * S_ + (kof),                             \
              ldsB + (bufoff) + (w4 + s) * 1024);                            \
  } while (0)

#define STAGE_A(dst, Z0, Z1) do {                                            \
    u16x4 a0v; a0v[0] = f2bf((Z0).x); a0v[1] = f2bf((Z0).y);                 \
    a0v[2] = f2bf((Z0).z); a0v[3] = f2bf((Z0).w);                            \
    u16x4 a1v; a1v[0] = f2bf((Z1).x); a1v[1] = f2bf((Z1).y);                 \
    a1v[2] = f2bf((Z1).z); a1v[3] = f2bf((Z1).w);                            \
    *(u16x4*)((dst) + (abyte0 ^ aswz)) = a0v;                                \
    *(u16x4*)((dst) + (abyte1 ^ aswz)) = a1v;                                \
  } while (0)

#define COMPUTE(Ac, Bc) do {                                                 \
    bf16x8 a0 = *(const bf16x8*)((Ac) + ((r0k * 128 + 0 + kb0) ^ ((r0k & 7) << 4)));   \
    bf16x8 a1 = *(const bf16x8*)((Ac) + ((r0k * 128 + 64 + kb0) ^ ((r0k & 7) << 4)));  \
    _Pragma("unroll")                                                        \
    for (int e = 0; e < 4; ++e) {                                            \
      int n = q * 64 + e * 16 + (lane & 15);                                 \
      bf16x8 bb0 = *(const bf16x8*)((Bc) + ((n * 128 + 0 + kb0) ^ ((n & 7) << 4)));  \
      bf16x8 bb1 = *(const bf16x8*)((Bc) + ((n * 128 + 64 + kb0) ^ ((n & 7) << 4))); \
      acc[e] = __builtin_amdgcn_mfma_f32_16x16x32_bf16(a0, bb0, acc[e], 0, 0, 0);    \
      acc[e] = __builtin_amdgcn_mfma_f32_16x16x32_bf16(a1, bb1, acc[e], 0, 0, 0);    \
    }                                                                        \
  } while (0)

  GLOAD_B(0, 0);
  {
    float4 z0 = *(const float4*)(zp);
    float4 z1 = *(const float4*)(zp + (size_t)16 * S_);
    STAGE_A(ldsA, z0, z1);
  }
  __syncthreads();

  for (int it = 0; it < NIT_; ++it) {
    const int cur = it & 1;
    const bool more = (it + 1 < NIT_);
    float4 z0, z1;
    if (more) {
      GLOAD_B((cur ^ 1) * 16384, (size_t)(it + 1) * KS_);
      z0 = *(const float4*)(zp + (it + 1) * KS_);
      z1 = *(const float4*)(zp + (size_t)16 * S_ + (it + 1) * KS_);
    }
    COMPUTE(ldsA + cur * 4096, ldsB + cur * 16384);
    if (more) STAGE_A(ldsA + (cur ^ 1) * 4096, z0, z1);
    __syncthreads();
  }
#undef GLOAD_B
#undef STAGE_A
#undef COMPUTE

  unsigned short* pout = part + (size_t)h * B_ * NP_;
#pragma unroll
  for (int e = 0; e < 4; ++e) {
    int col = q * 64 + e * 16 + (lane & 15);
#pragma unroll
    for (int i = 0; i < 4; ++i) {
      int r = m * 16 + ((lane >> 4) << 2) + i;
      pout[(size_t)(rowbase + r) * NP_ + col] = f2bf(acc[e][i]);
    }
  }

  // ---- last-arriver gate ----
  __threadfence();                       // release: partials -> device coherence point
  __syncthreads();                       // all threads' fences complete
  unsigned* flagp = (unsigned*)(lds + 4096 + 320);
  if (tid == 0) {
    unsigned old = atomicAdd(cnt + rt, 1u);
    *flagp = (old == 3u) ? 1u : 0u;
  }
  __syncthreads();
  if (*flagp == 0u) return;
  __threadfence();                       // acquire: invalidate stale L2 before reads

  // ---- k2 part: two 16-row halves of this row-tile ----
  const unsigned short* W2b = (const unsigned short*)(wsr + OFF_W2b);
  const unsigned short* W3cb = (const unsigned short*)(wsr + OFF_W3c);
  const float* b3c = (const float*)(wsr + OFF_b3c);
  float* s_part = (float*)(lds + 4096);          // [16][4]
  float* k_lds = (float*)(lds + 4096 + 256);     // [16]

  const int r0 = lane & 15;   // 16-row half: row within half

  for (int hr = 0; hr < 2; ++hr) {
    const int rb2 = rowbase + hr * 16;
    __syncthreads();   // prior LDS readers done

    // phase 1: reduce bf16 partials (fixed h order) + b1 + t*w1t, tanh -> h1 in ldsA
    {
      const int row = tid >> 4;           // 0..15
      const int col0 = (tid & 15) * 8;    // 0..120
      const unsigned short* p0 = part + (size_t)(rb2 + row) * NP_ + col0;
      float v[8];
#pragma unroll
      for (int j = 0; j < 8; ++j) v[j] = 0.0f;
#pragma unroll
      for (int hh = 0; hh < NSPLIT_; ++hh) {
        u16x8 u = *(const u16x8*)(p0 + (size_t)hh * B_ * NP_);
#pragma unroll
        for (int j = 0; j < 8; ++j) v[j] += bf2f(u[j]);
      }
      const float tv = t[rb2 + row];
      u16x8 o;
#pragma unroll
      for (int j = 0; j < 8; ++j) {
        int col = col0 + j;
        float b1c = (col < H_) ? b1[col] : 0.0f;
        float w1t = (col < H_) ? W1[col] : 0.0f;
        o[j] = f2bf(tanhf(v[j] + b1c + tv * w1t));
      }
      *(u16x8*)(ldsA + ((row * 256 + col0 * 2) ^ ((row & 7) << 4))) = o;
    }
    // stage W2 both K-halves: half kh -> ldsB + kh*16384, layout [128n][64k] swizzled
#pragma unroll
    for (int s = 0; s < 8; ++s) {
      int p = s * 256 + tid;      // 0..2047
      int kh = p >> 10;
      int j = p & 1023;
      int n = j >> 3, c = j & 7;
      s16x8 v2 = *(const s16x8*)(W2b + n * 128 + kh * 64 + c * 8);
      *(s16x8*)(ldsB + kh * 16384 + ((n * 128 + c * 16) ^ ((n & 7) << 4))) = v2;
    }
    if (tid < 64) s_part[tid] = 0.0f;
    __syncthreads();

    // GEMM2: K=128 as 2 halves (same MFMA order as K-major ks=0..3)
    f32x4 acc2[2];
    acc2[0] = f32x4{0.f, 0.f, 0.f, 0.f};
    acc2[1] = f32x4{0.f, 0.f, 0.f, 0.f};
#pragma unroll
    for (int kh = 0; kh < 2; ++kh) {
      bf16x8 a0 = *(const bf16x8*)(ldsA + ((r0 * 256 + kh * 128 + 0 + kb0) ^ ((r0 & 7) << 4)));
      bf16x8 a1 = *(const bf16x8*)(ldsA + ((r0 * 256 + kh * 128 + 64 + kb0) ^ ((r0 & 7) << 4)));
#pragma unroll
      for (int e = 0; e < 2; ++e) {
        int n = (w * 2 + e) * 16 + (lane & 15);
        bf16x8 b0 = *(const bf16x8*)(ldsB + kh * 16384 + ((n * 128 + 0 + kb0) ^ ((n & 7) << 4)));
        bf16x8 b1 = *(const bf16x8*)(ldsB + kh * 16384 + ((n * 128 + 64 + kb0) ^ ((n & 7) << 4)));
        acc2[e] = __builtin_amdgcn_mfma_f32_16x16x32_bf16(a0, b0, acc2[e], 0, 0, 0);
        acc2[e] = __builtin_amdgcn_mfma_f32_16x16x32_bf16(a1, b1, acc2[e], 0, 0, 0);
      }
    }
    __syncthreads();   // h1 + W2 reads done

    // h2 = tanh(acc2 + b2) -> ldsA; stage W3c step0 (ch0,kh0) -> ldsB[0]
#pragma unroll
    for (int e = 0; e < 2; ++e) {
      int col = (w * 2 + e) * 16 + (lane & 15);
      float b2c = (col < H_) ? b2[col] : 0.0f;
#pragma unroll
      for (int i = 0; i < 4; ++i) {
        int r = ((lane >> 4) << 2) + i;
        *(unsigned short*)(ldsA + ((r * 256 + col * 2) ^ ((r & 7) << 4))) =
            f2bf(tanhf(acc2[e][i] + b2c));
      }
    }
#pragma unroll
    for (int s = 0; s < 4; ++s) {
      int p = s * 256 + tid;
      int n = p >> 3, c = p & 7;
      s16x8 v3 = *(const s16x8*)(W3cb + (size_t)n * NP_ + c * 8);
      *(s16x8*)(ldsB + ((n * 128 + c * 16) ^ ((n & 7) << 4))) = v3;
    }
    __syncthreads();

    // af: h2 fragments (4 K-slices of 32)
    bf16x8 af[4];
#pragma unroll
    for (int j = 0; j < 4; ++j)
      af[j] = *(const bf16x8*)(ldsA + ((r0 * 256 + j * 64 + kb0) ^ ((r0 & 7) << 4)));

    f32x4 fr[16];
#pragma unroll
    for (int i = 0; i < 16; ++i) fr[i] = f32x4{0.f, 0.f, 0.f, 0.f};

    // GEMM3: 16 half-chunk steps (ch 0..7 x kh 0..1), 16KB dbuf, same MFMA order as R12
#pragma unroll
    for (int s = 0; s < 16; ++s) {
      const int ch = s >> 1, kh = s & 1;
      s16x8 st0, st1, st2, st3;
      if (s < 15) {
        const int ch2 = (s + 1) >> 1, kh2 = (s + 1) & 1;
        { int p = tid;       int n = p >> 3, c = p & 7; st0 = *(const s16x8*)(W3cb + (size_t)(ch2 * 128 + n) * NP_ + kh2 * 64 + c * 8); }
        { int p = 256 + tid; int n = p >> 3, c = p & 7; st1 = *(const s16x8*)(W3cb + (size_t)(ch2 * 128 + n) * NP_ + kh2 * 64 + c * 8); }
        { int p = 512 + tid; int n = p >> 3, c = p & 7; st2 = *(const s16x8*)(W3cb + (size_t)(ch2 * 128 + n) * NP_ + kh2 * 64 + c * 8); }
        { int p = 768 + tid; int n = p >> 3, c = p & 7; st3 = *(const s16x8*)(W3cb + (size_t)(ch2 * 128 + n) * NP_ + kh2 * 64 + c * 8); }
      }
      unsigned char* Bc = ldsB + (s & 1) * 16384;
#pragma unroll
      for (int e = 0; e < 2; ++e) {
        int nloc = (w + 4 * e) * 16 + (lane & 15);
        bf16x8 b0 = *(const bf16x8*)(Bc + ((nloc * 128 + 0 + kb0) ^ ((nloc & 7) << 4)));
        bf16x8 b1 = *(const bf16x8*)(Bc + ((nloc * 128 + 64 + kb0) ^ ((nloc & 7) << 4)));
        fr[ch * 2 + e] = __builtin_amdgcn_mfma_f32_16x16x32_bf16(af[kh * 2], b0, fr[ch * 2 + e], 0, 0, 0);
        fr[ch * 2 + e] = __builtin_amdgcn_mfma_f32_16x16x32_bf16(af[kh * 2 + 1], b1, fr[ch * 2 + e], 0, 0, 0);
      }
      if (s < 15) {
        unsigned char* Bn = ldsB + ((s + 1) & 1) * 16384;
        { int p = tid;       int n = p >> 3, c = p & 7; *(s16x8*)(Bn + ((n * 128 + c * 16) ^ ((n & 7) << 4))) = st0; }
        { int p = 256 + tid; int n = p >> 3, c = p & 7; *(s16x8*)(Bn + ((n * 128 + c * 16) ^ ((n & 7) << 4))) = st1; }
        { int p = 512 + tid; int n = p >> 3, c = p & 7; *(s16x8*)(Bn + ((n * 128 + c * 16) ^ ((n & 7) << 4))) = st2; }
        { int p = 768 + tid; int n = p >> 3, c = p & 7; *(s16x8*)(Bn + ((n * 128 + c * 16) ^ ((n & 7) << 4))) = st3; }
      }
      __syncthreads();
    }

    // bias, s = ||c||^2, k = f(W(s*256)), u = -k*c
#pragma unroll
    for (int fi = 0; fi < 16; ++fi) {
      int ch = fi >> 1, e = fi & 1;
      int col = ch * 128 + (w + 4 * e) * 16 + (lane & 15);
      float bc = b3c[col];
      fr[fi][0] += bc; fr[fi][1] += bc; fr[fi][2] += bc; fr[fi][3] += bc;
    }
#pragma unroll
    for (int i = 0; i < 4; ++i) {
      float v = 0.f;
#pragma unroll
      for (int fi = 0; fi < 16; ++fi) v += fr[fi][i] * fr[fi][i];
      v += __shfl_xor(v, 1);
      v += __shfl_xor(v, 2);
      v += __shfl_xor(v, 4);
      v += __shfl_xor(v, 8);
      if ((lane & 15) == 0) s_part[(((lane >> 4) << 2) + i) * 4 + w] = v;
    }
    __syncthreads();
    if (tid < 16) {
      float s = s_part[tid * 4 + 0] + s_part[tid * 4 + 1] + s_part[tid * 4 + 2] + s_part[tid * 4 + 3];
      float kk = 0.0f;
      if (s > 0.0f) {
        float wv = lambertw0(s * 256.0f);
        kk = sqrtf(wv * 256.0f / s);
      }
      k_lds[tid] = kk;
    }
    __syncthreads();
#pragma unroll
    for (int fi = 0; fi < 16; ++fi) {
      int ch = fi >> 1, e = fi & 1;
      int col = ch * 128 + (w + 4 * e) * 16 + (lane & 15);
#pragma unroll
      for (int i = 0; i < 4; ++i) {
        int r = ((lane >> 4) << 2) + i;
        uo[(size_t)(rb2 + r) * C_ + col] = -k_lds[r] * fr[fi][i];
      }
    }
  }
}

extern "C" void kernel_launch(void* const* d_in, const int* in_sizes, int n_in,
                              void* d_out, int out_size, void* d_ws, size_t ws_size,
                              hipStream_t stream) {
  const float* z  = (const float*)d_in[0];
  const float* t  = (const float*)d_in[1];
  const float* W1 = (const float*)d_in[2];
  const float* b1 = (const float*)d_in[3];
  const float* W2 = (const float*)d_in[4];
  const float* b2 = (const float*)d_in[5];
  const float* W3 = (const float*)d_in[6];
  const float* b3 = (const float*)d_in[7];
  float* out = (float*)d_out;
  unsigned char* ws = (unsigned char*)d_ws;
  unsigned short* part = (unsigned short*)(ws + OFF_part);
  unsigned int* cnt = (unsigned int*)(ws + OFF_cnt);

  constexpr int PREP_ELEMS = NP_ * S_ + NP_ * NP_ + C_ * NP_ + C_ + 256;
  k0_prep<<<(PREP_ELEMS + 255) / 256, 256, 0, stream>>>(W1, W2, W3, b3, ws);
  k1k2<<<B_ / 32 * NSPLIT_, 256, 0, stream>>>(z, t, W1, b1, b2, ws, part, cnt, out);
}

// Round 15
// 49.886 us; speedup vs baseline: 7.9453x; 7.9453x over previous
//
#include <hip/hip_runtime.h>

#define DEV __device__ __forceinline__

typedef __bf16 bf16x8 __attribute__((ext_vector_type(8)));
typedef float f32x4 __attribute__((ext_vector_type(4)));
typedef short s16x8 __attribute__((ext_vector_type(8)));
typedef unsigned short u16x4 __attribute__((ext_vector_type(4)));
typedef unsigned short u16x8 __attribute__((ext_vector_type(8)));

constexpr int B_ = 8192;   // batch
constexpr int S_ = 3072;   // z dim
constexpr int H_ = 100;    // hidden
constexpr int NP_ = 128;   // padded hidden
constexpr int C_ = 1024;   // control dim
constexpr int KS_ = 64;    // K-step for GEMM1
constexpr int NSPLIT_ = 4; // K-split factor
constexpr int KSP_ = S_ / NSPLIT_;       // 768 per split
constexpr int NIT_ = KSP_ / KS_;         // 12 iters per block

// workspace layout (bytes)
constexpr size_t OFF_W1b = 0;                                   // [128 n][3072 k] bf16
constexpr size_t OFF_W2b = OFF_W1b + (size_t)NP_ * S_ * 2;      // [128 n][128 k] bf16
constexpr size_t OFF_W3c = OFF_W2b + (size_t)NP_ * NP_ * 2;     // [1024 n][128 k] bf16
constexpr size_t OFF_b3c = OFF_W3c + (size_t)C_ * NP_ * 2;      // [1024] f32
constexpr size_t OFF_part = OFF_b3c + (size_t)C_ * 4;           // [4][8192][128] bf16 partials

DEV unsigned short f2bf(float f) {
  union { float f; unsigned u; } x; x.f = f;
  return (unsigned short)((x.u + 0x7FFFu + ((x.u >> 16) & 1u)) >> 16);
}

DEV float bf2f(unsigned short us) {
  union { unsigned u; float f; } x; x.u = ((unsigned)us) << 16;
  return x.f;
}

DEV float lambertw0(float x) {
  float w = log1pf(x);
#pragma unroll
  for (int i = 0; i < 10; ++i) {
    float ew = expf(w);
    float f = fmaf(w, ew, -x);
    float wp1 = w + 1.0f;
    float den = ew * wp1 - (w + 2.0f) * f / (2.0f * wp1);
    w = w - f / den;
  }
  return w;
}

DEV void gload16(const void* g, void* l) {
  __builtin_amdgcn_global_load_lds((const __attribute__((address_space(1))) unsigned int*)g,
                                   (__attribute__((address_space(3))) unsigned int*)l, 16, 0, 0);
}

// ---------------- prep: pack weights into bf16 n-major padded layouts ----------------
__global__ void k0_prep(const float* __restrict__ W1, const float* __restrict__ W2,
                        const float* __restrict__ W3, const float* __restrict__ b3,
                        unsigned char* __restrict__ ws) {
  int idx = blockIdx.x * 256 + threadIdx.x;
  constexpr int R1 = NP_ * S_;
  constexpr int R2 = R1 + NP_ * NP_;
  constexpr int R3 = R2 + C_ * NP_;
  constexpr int R4 = R3 + C_;
  if (idx < R1) {
    int n = idx / S_, k = idx - n * S_;
    float v = (n < H_) ? W1[(size_t)(k + 1) * H_ + n] : 0.0f;  // row 0 of W1 = t weights
    ((unsigned short*)(ws + OFF_W1b))[idx] = f2bf(v);
  } else if (idx < R2) {
    int j = idx - R1;
    int n = j >> 7, k = j & 127;
    float v = (n < H_ && k < H_) ? W2[(size_t)k * H_ + n] : 0.0f;
    ((unsigned short*)(ws + OFF_W2b))[j] = f2bf(v);
  } else if (idx < R3) {
    int j = idx - R2;
    int n = j >> 7, k = j & 127;
    float v = 0.0f;
    if (k < H_) {
      int a = n >> 2, cmp = n & 3;
      const float* row = W3 + (size_t)k * S_ + a * 12;
      v = (cmp == 0) ? 2.0f * (row[6] + row[7] + row[8]) : row[8 + cmp];  // /MASS = *2
    }
    ((unsigned short*)(ws + OFF_W3c))[j] = f2bf(v);
  } else if (idx < R4) {
    int n = idx - R3;
    int a = n >> 2, cmp = n & 3;
    const float* row = b3 + a * 12;
    float v = (cmp == 0) ? 2.0f * (row[6] + row[7] + row[8]) : row[8 + cmp];
    ((float*)(ws + OFF_b3c))[n] = v;
  }
}

// ---------------- K1: partial[h] = z[:, h*768:(h+1)*768] @ W1b[:, same]^T ----------------
// Proven 50.26us config (R13): B via gload_lds DMA (pre-swizzled source), A coalesced
// reg-staged, compiler-managed __syncthreads, bf16 partials.
__global__ __launch_bounds__(256, 4) void k1_gemm1(
    const float* __restrict__ z, const unsigned char* __restrict__ wsr,
    unsigned short* __restrict__ part) {
  __shared__ __align__(16) unsigned char lds[40 * 1024];
  unsigned char* ldsA = lds;          // 2 x 4KB  ([32 r][64 k] bf16, swizzled)
  unsigned char* ldsB = lds + 8192;   // 2 x 16KB ([128 n][64 k] bf16, swizzled)

  const int tid = threadIdx.x;
  const int lane = tid & 63;
  const int w = tid >> 6;
  const int m = w & 1;
  const int q = w >> 1;
  const int bid = blockIdx.x;
  const int rt = bid >> 2;
  const int h = bid & 3;
  const int rowbase = rt * 32;
  const int k0 = h * KSP_;

  const unsigned short* W1b = (const unsigned short*)(wsr + OFF_W1b);

  // A staging (coalesced): round 0 row = tid>>4, round 1 row = tid>>4 + 16;
  // col = (tid&15)*4 floats (16B contiguous per lane, 256B contiguous per row)
  const int arow0 = tid >> 4;             // 0..15
  const float* zp = z + (size_t)(rowbase + arow0) * S_ + k0 + (tid & 15) * 4;
  const int aswz = ((arow0 & 7) << 4);    // (row&7) identical for row and row+16
  const int abyte0 = arow0 * 128 + (tid & 15) * 8;
  const int abyte1 = (arow0 + 16) * 128 + (tid & 15) * 8;

  // B gload source: wave w, inst s covers rows (w*4+s)*8 + (lane>>3), physical chunk lane&7.
  // physical chunk p holds logical chunk p ^ (row&7)  ->  src chunk = (lane&7)^(lane>>3)
  const int w4 = w * 4;
  const unsigned short* bsrc = W1b + (size_t)(w4 * 8 + (lane >> 3)) * S_ + k0
                               + (((lane & 7) ^ (lane >> 3)) * 8);

  const int r0 = m * 16 + (lane & 15);
  const int kb0 = (lane >> 4) * 16;

  f32x4 acc[4];
#pragma unroll
  for (int e = 0; e < 4; ++e) acc[e] = f32x4{0.f, 0.f, 0.f, 0.f};

#define GLOAD_B(bufoff, kof) do {                                            \
    _Pragma("unroll")                                                        \
    for (int s = 0; s < 4; ++s)                                              \
      gload16(bsrc + (size_t)s * 8 * S_ + (kof),                             \
              ldsB + (bufoff) + (w4 + s) * 1024);                            \
  } while (0)

#define STAGE_A(dst, Z0, Z1) do {                                            \
    u16x4 a0; a0[0] = f2bf((Z0).x); a0[1] = f2bf((Z0).y);                    \
    a0[2] = f2bf((Z0).z); a0[3] = f2bf((Z0).w);                              \
    u16x4 a1; a1[0] = f2bf((Z1).x); a1[1] = f2bf((Z1).y);                    \
    a1[2] = f2bf((Z1).z); a1[3] = f2bf((Z1).w);                              \
    *(u16x4*)((dst) + (abyte0 ^ aswz)) = a0;                                 \
    *(u16x4*)((dst) + (abyte1 ^ aswz)) = a1;                                 \
  } while (0)

#define COMPUTE(Ac, Bc) do {                                                 \
    bf16x8 a0 = *(const bf16x8*)((Ac) + ((r0 * 128 + 0 + kb0) ^ ((r0 & 7) << 4)));   \
    bf16x8 a1 = *(const bf16x8*)((Ac) + ((r0 * 128 + 64 + kb0) ^ ((r0 & 7) << 4)));  \
    _Pragma("unroll")                                                        \
    for (int e = 0; e < 4; ++e) {                                            \
      int n = q * 64 + e * 16 + (lane & 15);                                 \
      bf16x8 bb0 = *(const bf16x8*)((Bc) + ((n * 128 + 0 + kb0) ^ ((n & 7) << 4)));  \
      bf16x8 bb1 = *(const bf16x8*)((Bc) + ((n * 128 + 64 + kb0) ^ ((n & 7) << 4))); \
      acc[e] = __builtin_amdgcn_mfma_f32_16x16x32_bf16(a0, bb0, acc[e], 0, 0, 0);    \
      acc[e] = __builtin_amdgcn_mfma_f32_16x16x32_bf16(a1, bb1, acc[e], 0, 0, 0);    \
    }                                                                        \
  } while (0)

  // prologue: B(0) -> bufB0 (DMA); z(0) rows 0-15 and 16-31 -> regs -> bufA0
  GLOAD_B(0, 0);
  {
    float4 z0 = *(const float4*)(zp);
    float4 z1 = *(const float4*)(zp + (size_t)16 * S_);
    STAGE_A(ldsA, z0, z1);
  }
  __syncthreads();   // drains vmcnt(0)+lgkmcnt(0): B(0) DMA + A(0) write visible

  for (int it = 0; it < NIT_; ++it) {
    const int cur = it & 1;
    const bool more = (it + 1 < NIT_);
    float4 z0, z1;
    if (more) {
      GLOAD_B((cur ^ 1) * 16384, (size_t)(it + 1) * KS_);  // B(t+1) DMA under compute
      z0 = *(const float4*)(zp + (it + 1) * KS_);
      z1 = *(const float4*)(zp + (size_t)16 * S_ + (it + 1) * KS_);
    }
    COMPUTE(ldsA + cur * 4096, ldsB + cur * 16384);
    if (more) STAGE_A(ldsA + (cur ^ 1) * 4096, z0, z1);
    __syncthreads();
  }
#undef GLOAD_B
#undef STAGE_A
#undef COMPUTE

  // write BF16 partial: part[h][rowbase+row][col]
  unsigned short* pout = part + (size_t)h * B_ * NP_;
#pragma unroll
  for (int e = 0; e < 4; ++e) {
    int col = q * 64 + e * 16 + (lane & 15);
#pragma unroll
    for (int i = 0; i < 4; ++i) {
      int r = m * 16 + ((lane >> 4) << 2) + i;
      pout[(size_t)(rowbase + r) * NP_ + col] = f2bf(acc[e][i]);
    }
  }
}

// ---------------- K2 fused: partial-reduce + GEMM2 + GEMM3 + LambertW head -------------
__global__ __launch_bounds__(512, 2) void k2_fused(
    const unsigned short* __restrict__ part, const float* __restrict__ t,
    const float* __restrict__ W1, const float* __restrict__ b1,
    const float* __restrict__ b2, const unsigned char* __restrict__ wsr,
    float* __restrict__ uo) {
  __shared__ __align__(16) unsigned char ldsA[8192];        // h1/h2 tile [32][128] bf16 swz
  __shared__ __align__(16) unsigned char ldsB[2][32768];    // W2 / W3c chunks
  __shared__ float s_part[32][4];
  __shared__ float k_lds[32];

  const int tid = threadIdx.x;
  const int lane = tid & 63;
  const int w = tid >> 6;
  const int m = w & 1;
  const int q = w >> 1;
  const int rowbase = blockIdx.x * 32;

  const unsigned short* W2b = (const unsigned short*)(wsr + OFF_W2b);
  const unsigned short* W3cb = (const unsigned short*)(wsr + OFF_W3c);
  const float* b3c = (const float*)(wsr + OFF_b3c);

  // phase 1: reduce bf16 partials (fixed h order) + b1 + t*w1t, tanh -> ldsA (h1)
  {
    const int row = tid >> 4;           // 0..31
    const int col0 = (tid & 15) * 8;    // 0..120
    const unsigned short* p0 = part + (size_t)(rowbase + row) * NP_ + col0;
    float v[8];
#pragma unroll
    for (int j = 0; j < 8; ++j) v[j] = 0.0f;
#pragma unroll
    for (int hh = 0; hh < NSPLIT_; ++hh) {
      u16x8 u = *(const u16x8*)(p0 + (size_t)hh * B_ * NP_);
#pragma unroll
      for (int j = 0; j < 8; ++j) v[j] += bf2f(u[j]);
    }
    const float tv = t[rowbase + row];
    u16x8 o;
#pragma unroll
    for (int j = 0; j < 8; ++j) {
      int col = col0 + j;
      float b1c = (col < H_) ? b1[col] : 0.0f;
      float w1t = (col < H_) ? W1[col] : 0.0f;
      float pre = v[j] + b1c + tv * w1t;
      o[j] = f2bf(tanhf(pre));
    }
    *(u16x8*)(ldsA + ((row * 256 + col0 * 2) ^ ((row & 7) << 4))) = o;
  }
  // stage W2 -> ldsB[1], W3c chunk0 -> ldsB[0]
#pragma unroll
  for (int s = 0; s < 4; ++s) {
    int p = s * 512 + tid;
    int n = p >> 4, k16 = p & 15;
    s16x8 v2 = *(const s16x8*)(W2b + n * 128 + k16 * 8);
    *(s16x8*)(ldsB[1] + ((n * 256 + k16 * 16) ^ ((n & 7) << 4))) = v2;
    s16x8 v3 = *(const s16x8*)(W3cb + (size_t)n * NP_ + k16 * 8);
    *(s16x8*)(ldsB[0] + ((n * 256 + k16 * 16) ^ ((n & 7) << 4))) = v3;
  }
  if (tid < 128) s_part[tid >> 2][tid & 3] = 0.0f;
  __syncthreads();

  const int r0 = m * 16 + (lane & 15);
  const int kb0 = (lane >> 4) * 16;

  // GEMM2: K=128, cols split over 8 waves as (q*2+e)*16
  f32x4 acc2[2];
  acc2[0] = f32x4{0.f, 0.f, 0.f, 0.f};
  acc2[1] = f32x4{0.f, 0.f, 0.f, 0.f};
#pragma unroll
  for (int ks = 0; ks < 4; ++ks) {
    bf16x8 a = *(const bf16x8*)(ldsA + ((r0 * 256 + ks * 64 + kb0) ^ ((r0 & 7) << 4)));
#pragma unroll
    for (int e = 0; e < 2; ++e) {
      int n = (q * 2 + e) * 16 + (lane & 15);
      bf16x8 b = *(const bf16x8*)(ldsB[1] + ((n * 256 + ks * 64 + kb0) ^ ((n & 7) << 4)));
      acc2[e] = __builtin_amdgcn_mfma_f32_16x16x32_bf16(a, b, acc2[e], 0, 0, 0);
    }
  }
  __syncthreads();   // all h1/W2 reads done
  // h2 = tanh(acc2 + b2) -> ldsA
#pragma unroll
  for (int e = 0; e < 2; ++e) {
    int col = (q * 2 + e) * 16 + (lane & 15);
    float b2c = (col < H_) ? b2[col] : 0.0f;
#pragma unroll
    for (int i = 0; i < 4; ++i) {
      int r = m * 16 + ((lane >> 4) << 2) + i;
      float hh = tanhf(acc2[e][i] + b2c);
      *(unsigned short*)(ldsA + ((r * 256 + col * 2) ^ ((r & 7) << 4))) = f2bf(hh);
    }
  }
  __syncthreads();   // h2 visible to all

  // GEMM3: c = h2 @ W3c + b3c, streaming 8 chunks of 128 cols
  bf16x8 af[4];
#pragma unroll
  for (int ks = 0; ks < 4; ++ks)
    af[ks] = *(const bf16x8*)(ldsA + ((r0 * 256 + ks * 64 + kb0) ^ ((r0 & 7) << 4)));

  f32x4 fr[16];
#pragma unroll
  for (int i = 0; i < 16; ++i) fr[i] = f32x4{0.f, 0.f, 0.f, 0.f};

#pragma unroll 8
  for (int ch = 0; ch < 8; ++ch) {
    const int cur = ch & 1;
    const bool more = ch < 7;
    s16x8 st0, st1, st2, st3;
    if (more) {
      int base = (ch + 1) * 128;
      { int p = tid;            int n = p >> 4, k16 = p & 15; st0 = *(const s16x8*)(W3cb + (size_t)(base + n) * NP_ + k16 * 8); }
      { int p = 512 + tid;      int n = p >> 4, k16 = p & 15; st1 = *(const s16x8*)(W3cb + (size_t)(base + n) * NP_ + k16 * 8); }
      { int p = 1024 + tid;     int n = p >> 4, k16 = p & 15; st2 = *(const s16x8*)(W3cb + (size_t)(base + n) * NP_ + k16 * 8); }
      { int p = 1536 + tid;     int n = p >> 4, k16 = p & 15; st3 = *(const s16x8*)(W3cb + (size_t)(base + n) * NP_ + k16 * 8); }
    }
#pragma unroll
    for (int e = 0; e < 2; ++e) {
      int nloc = (q + 4 * e) * 16 + (lane & 15);
#pragma unroll
      for (int ks = 0; ks < 4; ++ks) {
        bf16x8 b = *(const bf16x8*)(ldsB[cur] + ((nloc * 256 + ks * 64 + kb0) ^ ((nloc & 7) << 4)));
        fr[ch * 2 + e] = __builtin_amdgcn_mfma_f32_16x16x32_bf16(af[ks], b, fr[ch * 2 + e], 0, 0, 0);
      }
    }
    if (more) {
      unsigned char* Bn = ldsB[cur ^ 1];
      { int p = tid;        int n = p >> 4, k16 = p & 15; *(s16x8*)(Bn + ((n * 256 + k16 * 16) ^ ((n & 7) << 4))) = st0; }
      { int p = 512 + tid;  int n = p >> 4, k16 = p & 15; *(s16x8*)(Bn + ((n * 256 + k16 * 16) ^ ((n & 7) << 4))) = st1; }
      { int p = 1024 + tid; int n = p >> 4, k16 = p & 15; *(s16x8*)(Bn + ((n * 256 + k16 * 16) ^ ((n & 7) << 4))) = st2; }
      { int p = 1536 + tid; int n = p >> 4, k16 = p & 15; *(s16x8*)(Bn + ((n * 256 + k16 * 16) ^ ((n & 7) << 4))) = st3; }
    }
    __syncthreads();
  }

  // bias, s = ||c||^2, k = f(W(s*256)), u = -k*c
#pragma unroll
  for (int fi = 0; fi < 16; ++fi) {
    int ch = fi >> 1, e = fi & 1;
    int col = (ch * 8 + q + 4 * e) * 16 + (lane & 15);
    float bc = b3c[col];
    fr[fi][0] += bc; fr[fi][1] += bc; fr[fi][2] += bc; fr[fi][3] += bc;
  }
#pragma unroll
  for (int i = 0; i < 4; ++i) {
    float v = 0.f;
#pragma unroll
    for (int fi = 0; fi < 16; ++fi) v += fr[fi][i] * fr[fi][i];
    v += __shfl_xor(v, 1);
    v += __shfl_xor(v, 2);
    v += __shfl_xor(v, 4);
    v += __shfl_xor(v, 8);
    if ((lane & 15) == 0) s_part[m * 16 + ((lane >> 4) << 2) + i][q] = v;
  }
  __syncthreads();
  if (tid < 32) {
    float s = s_part[tid][0] + s_part[tid][1] + s_part[tid][2] + s_part[tid][3];
    float kk = 0.0f;
    if (s > 0.0f) {
      float wv = lambertw0(s * 256.0f);
      kk = sqrtf(wv * 256.0f / s);
    }
    k_lds[tid] = kk;
  }
  __syncthreads();
#pragma unroll
  for (int fi = 0; fi < 16; ++fi) {
    int ch = fi >> 1, e = fi & 1;
    int col = (ch * 8 + q + 4 * e) * 16 + (lane & 15);
#pragma unroll
    for (int i = 0; i < 4; ++i) {
      int r = m * 16 + ((lane >> 4) << 2) + i;
      uo[(size_t)(rowbase + r) * C_ + col] = -k_lds[r] * fr[fi][i];
    }
  }
}

extern "C" void kernel_launch(void* const* d_in, const int* in_sizes, int n_in,
                              void* d_out, int out_size, void* d_ws, size_t ws_size,
                              hipStream_t stream) {
  const float* z  = (const float*)d_in[0];
  const float* t  = (const float*)d_in[1];
  const float* W1 = (const float*)d_in[2];
  const float* b1 = (const float*)d_in[3];
  const float* W2 = (const float*)d_in[4];
  const float* b2 = (const float*)d_in[5];
  const float* W3 = (const float*)d_in[6];
  const float* b3 = (const float*)d_in[7];
  float* out = (float*)d_out;
  unsigned char* ws = (unsigned char*)d_ws;
  unsigned short* part = (unsigned short*)(ws + OFF_part);   // 8 MB bf16 partials

  constexpr int PREP_ELEMS = NP_ * S_ + NP_ * NP_ + C_ * NP_ + C_;
  k0_prep<<<(PREP_ELEMS + 255) / 256, 256, 0, stream>>>(W1, W2, W3, b3, ws);
  k1_gemm1<<<B_ / 32 * NSPLIT_, 256, 0, stream>>>(z, ws, part);
  k2_fused<<<B_ / 32, 512, 0, stream>>>(part, t, W1, b1, b2, ws, out);
}